// Round 1
// baseline (580.519 us; speedup 1.0000x reference)
//
#include <hip/hip_runtime.h>
#include <hip/hip_bf16.h>

#define HH 8
#define NB 2048
#define MB 2048

typedef __attribute__((ext_vector_type(8))) short short8;
typedef __attribute__((ext_vector_type(4))) float floatx4;

__device__ __forceinline__ unsigned short f2bf(float f) {
    union { float f; unsigned int u; } v; v.f = f;
    unsigned int r = (v.u + 0x7FFFu + ((v.u >> 16) & 1u)) >> 16;
    return (unsigned short)r;
}

// XOR-swizzled LDS layout: row-major, 64 elems/row, 16B chunks swizzled by row.
// Guarantees <=2-way bank conflicts for both staged writes and MFMA frag reads.
__device__ __forceinline__ int swz(int row, int k) {
    return (row << 6) + ((((k >> 3) ^ (row & 7))) << 3) + (k & 7);
}

// ---------------------------------------------------------------------------
// Generic 128x128-tile bf16 MFMA GEMM, K=512 fixed, A row-major [Mr,512],
// B row-major [512,Nc]. A_BF16: A is bf16 (else fp32, converted in staging).
// OUT_BF16: store bf16, else fp32 + bias.
// ---------------------------------------------------------------------------
template <int A_BF16, int OUT_BF16>
__launch_bounds__(256)
__global__ void gemm_proj(const void* __restrict__ Ap, const float* __restrict__ Bp,
                          const float* __restrict__ bias, void* __restrict__ Cp, int Nc) {
    __shared__ short Alds[128 * 64];
    __shared__ short Blds[128 * 64];

    const int tid = threadIdx.x;
    const int w = tid >> 6, lane = tid & 63;
    const int quad = lane >> 4, c16 = lane & 15;
    const int wr = (w >> 1) * 64, wc = (w & 1) * 64;
    const int m0 = blockIdx.x * 128, n0 = blockIdx.y * 128;

    const float* Af = (const float*)Ap;
    const unsigned short* Ab = (const unsigned short*)Ap;

    floatx4 acc[4][4];
#pragma unroll
    for (int i = 0; i < 4; i++)
#pragma unroll
        for (int j = 0; j < 4; j++) acc[i][j] = floatx4{0.f, 0.f, 0.f, 0.f};

    for (int kk = 0; kk < 512; kk += 64) {
        __syncthreads();
        // Stage A tile: 128 rows x 64 k (fp32->bf16 or bf16 passthrough)
#pragma unroll
        for (int p = 0; p < 8; p++) {
            int id = p * 256 + tid;
            int row = id >> 4, k4 = (id & 15) << 2;
            uint2 pk;
            if (A_BF16) {
                pk = *(const uint2*)(Ab + (size_t)(m0 + row) * 512 + kk + k4);
            } else {
                float4 d = *(const float4*)(Af + (size_t)(m0 + row) * 512 + kk + k4);
                pk.x = (unsigned int)f2bf(d.x) | ((unsigned int)f2bf(d.y) << 16);
                pk.y = (unsigned int)f2bf(d.z) | ((unsigned int)f2bf(d.w) << 16);
            }
            *(uint2*)&Alds[swz(row, k4)] = pk;
        }
        // Stage B tile transposed: Blds[n][k] = B[k][n], 64 k-rows x 128 n
#pragma unroll
        for (int p = 0; p < 8; p++) {
            int id = p * 256 + tid;
            int kr = id >> 5, n4 = (id & 31) << 2;
            float4 d = *(const float4*)(Bp + (size_t)(kk + kr) * Nc + n0 + n4);
            Blds[swz(n4 + 0, kr)] = (short)f2bf(d.x);
            Blds[swz(n4 + 1, kr)] = (short)f2bf(d.y);
            Blds[swz(n4 + 2, kr)] = (short)f2bf(d.z);
            Blds[swz(n4 + 3, kr)] = (short)f2bf(d.w);
        }
        __syncthreads();
#pragma unroll
        for (int kc = 0; kc < 2; kc++) {
            short8 af[4], bf[4];
#pragma unroll
            for (int mt = 0; mt < 4; mt++)
                af[mt] = *(const short8*)&Alds[swz(wr + mt * 16 + c16, kc * 32 + quad * 8)];
#pragma unroll
            for (int nt = 0; nt < 4; nt++)
                bf[nt] = *(const short8*)&Blds[swz(wc + nt * 16 + c16, kc * 32 + quad * 8)];
#pragma unroll
            for (int mt = 0; mt < 4; mt++)
#pragma unroll
                for (int nt = 0; nt < 4; nt++)
                    acc[mt][nt] = __builtin_amdgcn_mfma_f32_16x16x32_bf16(af[mt], bf[nt], acc[mt][nt], 0, 0, 0);
        }
    }
    // Epilogue: C/D layout col=lane&15, row=quad*4+reg
#pragma unroll
    for (int mt = 0; mt < 4; mt++)
#pragma unroll
        for (int nt = 0; nt < 4; nt++)
#pragma unroll
            for (int r = 0; r < 4; r++) {
                int row = m0 + wr + mt * 16 + quad * 4 + r;
                int col = n0 + wc + nt * 16 + c16;
                float v = acc[mt][nt][r];
                if (OUT_BF16) {
                    ((unsigned short*)Cp)[(size_t)row * Nc + col] = f2bf(v);
                } else {
                    ((float*)Cp)[(size_t)row * Nc + col] = v + bias[col];
                }
            }
}

// ---------------------------------------------------------------------------
// Flash attention (no running max: |dots| <= ~7 so exp() is safe in fp32).
// Block: 64 Q-rows (4 waves x 16 rows), M-tiles of 64 staged in LDS.
// q,v from qv buffer [B*N,1024] bf16 (q cols 0..511, v cols 512..1023),
// k from [B*M,512] bf16. Output attn_out bf16 [B*N,512].
// ---------------------------------------------------------------------------
__launch_bounds__(256)
__global__ void flash_attn(const unsigned short* __restrict__ qv,
                           const unsigned short* __restrict__ kb,
                           const float* __restrict__ attn_mat,
                           const float* __restrict__ dots_para,
                           const float* __restrict__ mat_para,
                           unsigned short* __restrict__ ao) {
    __shared__ short Qs[64 * 64];
    __shared__ short Ks[64 * 64];
    __shared__ short Vs[64 * 64];  // transposed: Vs[d][m]
    __shared__ short Ps[4][16 * 64];

    const int tid = threadIdx.x, w = tid >> 6, lane = tid & 63;
    const int quad = lane >> 4, c16 = lane & 15;
    const int q0 = blockIdx.x * 64;
    const int bh = blockIdx.y;
    const int b = bh >> 3, h = bh & 7;

    const float mp = mat_para[0];
    const float sdp = dots_para[0] * 0.125f;  // scale = DH^-0.5 = 1/8

    // Stage Q (64 rows x 64 d)
    for (int id = tid; id < 512; id += 256) {
        int r = id >> 3, c = id & 7;
        *(uint4*)&Qs[swz(r, c * 8)] =
            *(const uint4*)(qv + (size_t)(b * NB + q0 + r) * 1024 + h * 64 + c * 8);
    }
    __syncthreads();
    short8 qf0 = *(const short8*)&Qs[swz(w * 16 + c16, quad * 8)];
    short8 qf1 = *(const short8*)&Qs[swz(w * 16 + c16, 32 + quad * 8)];

    floatx4 O[4];
    float l[4] = {0.f, 0.f, 0.f, 0.f};
#pragma unroll
    for (int dt = 0; dt < 4; dt++) O[dt] = floatx4{0.f, 0.f, 0.f, 0.f};

    const float* am_base = attn_mat + ((size_t)bh * NB + q0 + w * 16 + quad * 4) * MB;

    for (int m0 = 0; m0 < MB; m0 += 64) {
        __syncthreads();
        // Stage K tile
        for (int id = tid; id < 512; id += 256) {
            int r = id >> 3, c = id & 7;
            *(uint4*)&Ks[swz(r, c * 8)] =
                *(const uint4*)(kb + (size_t)(b * MB + m0 + r) * 512 + h * 64 + c * 8);
        }
        // Stage V tile transposed: Vs[d][m]
        for (int id = tid; id < 512; id += 256) {
            int r = id >> 3, c = id & 7;  // r = m-row, c*8 = d0
            uint4 d = *(const uint4*)(qv + (size_t)(b * NB + m0 + r) * 1024 + 512 + h * 64 + c * 8);
            Vs[swz(c * 8 + 0, r)] = (short)(d.x & 0xffff);
            Vs[swz(c * 8 + 1, r)] = (short)(d.x >> 16);
            Vs[swz(c * 8 + 2, r)] = (short)(d.y & 0xffff);
            Vs[swz(c * 8 + 3, r)] = (short)(d.y >> 16);
            Vs[swz(c * 8 + 4, r)] = (short)(d.z & 0xffff);
            Vs[swz(c * 8 + 5, r)] = (short)(d.z >> 16);
            Vs[swz(c * 8 + 6, r)] = (short)(d.w & 0xffff);
            Vs[swz(c * 8 + 7, r)] = (short)(d.w >> 16);
        }
        __syncthreads();

        // attn_mat loads (issued early to overlap with QK^T)
        float am[4][4];
#pragma unroll
        for (int t = 0; t < 4; t++)
#pragma unroll
            for (int r = 0; r < 4; r++)
                am[t][r] = am_base[(size_t)r * MB + m0 + t * 16 + c16];

        // S = Q K^T  (16 rows x 64 keys)
        floatx4 S[4];
#pragma unroll
        for (int t = 0; t < 4; t++) {
            short8 kf0 = *(const short8*)&Ks[swz(t * 16 + c16, quad * 8)];
            short8 kf1 = *(const short8*)&Ks[swz(t * 16 + c16, 32 + quad * 8)];
            floatx4 s = floatx4{0.f, 0.f, 0.f, 0.f};
            s = __builtin_amdgcn_mfma_f32_16x16x32_bf16(qf0, kf0, s, 0, 0, 0);
            s = __builtin_amdgcn_mfma_f32_16x16x32_bf16(qf1, kf1, s, 0, 0, 0);
            S[t] = s;
        }

        // P = exp(S*scale*dots_para + attn*mat_para); accumulate row sums; C->A layout via LDS
#pragma unroll
        for (int t = 0; t < 4; t++)
#pragma unroll
            for (int r = 0; r < 4; r++) {
                float p = __expf(fmaf(S[t][r], sdp, am[t][r] * mp));
                l[r] += p;
                Ps[w][swz(quad * 4 + r, t * 16 + c16)] = (short)f2bf(p);
            }
        __threadfence_block();  // order our wave's LDS writes before reads
        short8 pf0 = *(const short8*)&Ps[w][swz(c16, quad * 8)];
        short8 pf1 = *(const short8*)&Ps[w][swz(c16, 32 + quad * 8)];

        // O += P V
#pragma unroll
        for (int dt = 0; dt < 4; dt++) {
            short8 vf0 = *(const short8*)&Vs[swz(dt * 16 + c16, quad * 8)];
            short8 vf1 = *(const short8*)&Vs[swz(dt * 16 + c16, 32 + quad * 8)];
            O[dt] = __builtin_amdgcn_mfma_f32_16x16x32_bf16(pf0, vf0, O[dt], 0, 0, 0);
            O[dt] = __builtin_amdgcn_mfma_f32_16x16x32_bf16(pf1, vf1, O[dt], 0, 0, 0);
        }
    }

    // Row sums: reduce across the 16 lanes of each quad (cols), then invert
#pragma unroll
    for (int r = 0; r < 4; r++) {
        float s = l[r];
        s += __shfl_xor(s, 1);
        s += __shfl_xor(s, 2);
        s += __shfl_xor(s, 4);
        s += __shfl_xor(s, 8);
        l[r] = 1.0f / s;
    }
#pragma unroll
    for (int dt = 0; dt < 4; dt++)
#pragma unroll
        for (int r = 0; r < 4; r++) {
            int row = b * NB + q0 + w * 16 + quad * 4 + r;
            ao[(size_t)row * 512 + h * 64 + dt * 16 + c16] = f2bf(O[dt][r] * l[r]);
        }
}

extern "C" void kernel_launch(void* const* d_in, const int* in_sizes, int n_in,
                              void* d_out, int out_size, void* d_ws, size_t ws_size,
                              hipStream_t stream) {
    const float* x         = (const float*)d_in[0];
    const float* x1        = (const float*)d_in[1];
    const float* attn_mat  = (const float*)d_in[2];
    const float* dots_para = (const float*)d_in[3];
    const float* mat_para  = (const float*)d_in[4];
    const float* W_qv      = (const float*)d_in[5];
    const float* W_k       = (const float*)d_in[6];
    const float* W_out     = (const float*)d_in[7];
    const float* b_out     = (const float*)d_in[8];
    float* out = (float*)d_out;

    unsigned short* qvbf = (unsigned short*)d_ws;          // [4096,1024] bf16 (q|v)
    unsigned short* kbf  = qvbf + (size_t)4096 * 1024;     // [4096,512]  bf16
    unsigned short* aobf = kbf + (size_t)4096 * 512;       // [4096,512]  bf16

    dim3 blk(256);
    gemm_proj<0, 1><<<dim3(32, 8), blk, 0, stream>>>(x, W_qv, nullptr, qvbf, 1024);
    gemm_proj<0, 1><<<dim3(32, 4), blk, 0, stream>>>(x1, W_k, nullptr, kbf, 512);
    flash_attn<<<dim3(32, 16), blk, 0, stream>>>(qvbf, kbf, attn_mat, dots_para, mat_para, aobf);
    gemm_proj<1, 0><<<dim3(32, 4), blk, 0, stream>>>(aobf, W_out, b_out, out, 512);
}

// Round 2
// 464.634 us; speedup vs baseline: 1.2494x; 1.2494x over previous
//
#include <hip/hip_runtime.h>
#include <hip/hip_bf16.h>

#define NB 2048
#define MB 2048

typedef __attribute__((ext_vector_type(8))) short short8;
typedef __attribute__((ext_vector_type(4))) float floatx4;

__device__ __forceinline__ unsigned short f2bf(float f) {
    union { float f; unsigned int u; } v; v.f = f;
    unsigned int r = (v.u + 0x7FFFu + ((v.u >> 16) & 1u)) >> 16;
    return (unsigned short)r;
}

// XOR-swizzled LDS layout: row-major, 64 elems/row, 16B chunks swizzled by row low bits.
__device__ __forceinline__ int swz(int row, int k) {
    return (row << 6) + ((((k >> 3) ^ (row & 7))) << 3) + (k & 7);
}
// Variant for transposed-V: xor includes row bits [5:3] so the d-major transpose
// stores (row = c*8+i -> row&7 == i for all lanes) still spread across banks.
__device__ __forceinline__ int vswz(int row, int k) {
    return (row << 6) + ((((k >> 3) ^ (row & 7) ^ ((row >> 3) & 7))) << 3) + (k & 7);
}

// ---------------------------------------------------------------------------
// fp32 -> bf16 elementwise (x, x1)
// ---------------------------------------------------------------------------
__launch_bounds__(256)
__global__ void cvt_bf16(const float* __restrict__ in, unsigned short* __restrict__ out, int n4) {
    int idx = blockIdx.x * 256 + threadIdx.x;
    if (idx >= n4) return;
    float4 d = *(const float4*)(in + (size_t)idx * 4);
    uint2 o;
    o.x = (unsigned int)f2bf(d.x) | ((unsigned int)f2bf(d.y) << 16);
    o.y = (unsigned int)f2bf(d.z) | ((unsigned int)f2bf(d.w) << 16);
    *(uint2*)(out + (size_t)idx * 4) = o;
}

// ---------------------------------------------------------------------------
// W [K][N] fp32 -> Wt [N][K] bf16  (64x64 tiles)
// ---------------------------------------------------------------------------
__launch_bounds__(256)
__global__ void transpose_cvt(const float* __restrict__ W, unsigned short* __restrict__ Wt,
                              int K, int N) {
    __shared__ float t[64][65];
    const int tid = threadIdx.x;
    const int k0 = blockIdx.x * 64, n0 = blockIdx.y * 64;
#pragma unroll
    for (int p = 0; p < 4; p++) {
        int idx = p * 256 + tid;
        int kr = idx >> 4, c4 = (idx & 15) << 2;
        float4 d = *(const float4*)(W + (size_t)(k0 + kr) * N + n0 + c4);
        t[kr][c4 + 0] = d.x; t[kr][c4 + 1] = d.y; t[kr][c4 + 2] = d.z; t[kr][c4 + 3] = d.w;
    }
    __syncthreads();
#pragma unroll
    for (int p = 0; p < 4; p++) {
        int idx = p * 256 + tid;
        int nr = idx >> 4, k4 = (idx & 15) << 2;
        uint2 o;
        o.x = (unsigned int)f2bf(t[k4 + 0][nr]) | ((unsigned int)f2bf(t[k4 + 1][nr]) << 16);
        o.y = (unsigned int)f2bf(t[k4 + 2][nr]) | ((unsigned int)f2bf(t[k4 + 3][nr]) << 16);
        *(uint2*)(Wt + (size_t)(n0 + nr) * K + k0 + k4) = o;
    }
}

// ---------------------------------------------------------------------------
// bf16 GEMM: A [M][512] row-major, Bt [N][512] row-major (pre-transposed),
// C = A @ Bt^T.  64x64 tile, BK=64, 256 threads (4 waves, each 32x32).
// ---------------------------------------------------------------------------
template <int OUT_BF16>
__launch_bounds__(256)
__global__ void gemm_bt(const unsigned short* __restrict__ A, const unsigned short* __restrict__ Bt,
                        const float* __restrict__ bias, void* __restrict__ Cp, int Nc) {
    __shared__ short Al[64 * 64];
    __shared__ short Bl[64 * 64];

    const int tid = threadIdx.x;
    const int w = tid >> 6, lane = tid & 63;
    const int quad = lane >> 4, c16 = lane & 15;
    const int wr = (w >> 1) * 32, wc = (w & 1) * 32;
    const int m0 = blockIdx.x * 64, n0 = blockIdx.y * 64;

    floatx4 acc[2][2];
#pragma unroll
    for (int i = 0; i < 2; i++)
#pragma unroll
        for (int j = 0; j < 2; j++) acc[i][j] = floatx4{0.f, 0.f, 0.f, 0.f};

    for (int kk = 0; kk < 512; kk += 64) {
        __syncthreads();
#pragma unroll
        for (int p = 0; p < 2; p++) {
            int id = p * 256 + tid;
            int row = id >> 3, c8 = (id & 7) << 3;
            *(uint4*)&Al[swz(row, c8)] = *(const uint4*)(A + (size_t)(m0 + row) * 512 + kk + c8);
            *(uint4*)&Bl[swz(row, c8)] = *(const uint4*)(Bt + (size_t)(n0 + row) * 512 + kk + c8);
        }
        __syncthreads();
#pragma unroll
        for (int kc = 0; kc < 2; kc++) {
            short8 af[2], bf[2];
#pragma unroll
            for (int mt = 0; mt < 2; mt++)
                af[mt] = *(const short8*)&Al[swz(wr + mt * 16 + c16, kc * 32 + quad * 8)];
#pragma unroll
            for (int nt = 0; nt < 2; nt++)
                bf[nt] = *(const short8*)&Bl[swz(wc + nt * 16 + c16, kc * 32 + quad * 8)];
#pragma unroll
            for (int mt = 0; mt < 2; mt++)
#pragma unroll
                for (int nt = 0; nt < 2; nt++)
                    acc[mt][nt] = __builtin_amdgcn_mfma_f32_16x16x32_bf16(af[mt], bf[nt], acc[mt][nt], 0, 0, 0);
        }
    }
#pragma unroll
    for (int mt = 0; mt < 2; mt++)
#pragma unroll
        for (int nt = 0; nt < 2; nt++)
#pragma unroll
            for (int r = 0; r < 4; r++) {
                int row = m0 + wr + mt * 16 + quad * 4 + r;
                int col = n0 + wc + nt * 16 + c16;
                float v = acc[mt][nt][r];
                if (OUT_BF16) {
                    ((unsigned short*)Cp)[(size_t)row * Nc + col] = f2bf(v);
                } else {
                    ((float*)Cp)[(size_t)row * Nc + col] = v + bias[col];
                }
            }
}

// ---------------------------------------------------------------------------
// Flash attention, M split into 2 halves (blockIdx.z). Unnormalized partial
// O (fp32) and row-sum l written to workspace; combine kernel normalizes.
// No running max: |dots| <= ~7 so exp() is safe in fp32.
// ---------------------------------------------------------------------------
__launch_bounds__(256)
__global__ void flash_attn(const unsigned short* __restrict__ qv,
                           const unsigned short* __restrict__ kb,
                           const float* __restrict__ attn_mat,
                           const float* __restrict__ dots_para,
                           const float* __restrict__ mat_para,
                           float* __restrict__ Opart,
                           float* __restrict__ lpart) {
    __shared__ short Qs[64 * 64];
    __shared__ short Ks[64 * 64];
    __shared__ short Vs[64 * 64];  // transposed: Vs[d][m], vswz layout
    __shared__ short Ps[4][16 * 64];

    const int tid = threadIdx.x, w = tid >> 6, lane = tid & 63;
    const int quad = lane >> 4, c16 = lane & 15;
    const int q0 = blockIdx.x * 64;
    const int bh = blockIdx.y;
    const int sp = blockIdx.z;                 // M-split index
    const int b = bh >> 3, h = bh & 7;
    const int ms = sp * (MB / 2);

    const float mp = mat_para[0];
    const float sdp = dots_para[0] * 0.125f;   // scale = DH^-0.5 = 1/8

    for (int id = tid; id < 512; id += 256) {
        int r = id >> 3, c = id & 7;
        *(uint4*)&Qs[swz(r, c * 8)] =
            *(const uint4*)(qv + (size_t)(b * NB + q0 + r) * 1024 + h * 64 + c * 8);
    }
    __syncthreads();
    short8 qf0 = *(const short8*)&Qs[swz(w * 16 + c16, quad * 8)];
    short8 qf1 = *(const short8*)&Qs[swz(w * 16 + c16, 32 + quad * 8)];

    floatx4 O[4];
    float l[4] = {0.f, 0.f, 0.f, 0.f};
#pragma unroll
    for (int dt = 0; dt < 4; dt++) O[dt] = floatx4{0.f, 0.f, 0.f, 0.f};

    const float* am_base = attn_mat + ((size_t)bh * NB + q0 + w * 16 + quad * 4) * MB;

    for (int m0 = ms; m0 < ms + MB / 2; m0 += 64) {
        __syncthreads();
        for (int id = tid; id < 512; id += 256) {
            int r = id >> 3, c = id & 7;
            *(uint4*)&Ks[swz(r, c * 8)] =
                *(const uint4*)(kb + (size_t)(b * MB + m0 + r) * 512 + h * 64 + c * 8);
        }
        for (int id = tid; id < 512; id += 256) {
            int r = id >> 3, c = id & 7;  // r = m-row, c*8 = d0
            uint4 d = *(const uint4*)(qv + (size_t)(b * NB + m0 + r) * 1024 + 512 + h * 64 + c * 8);
            Vs[vswz(c * 8 + 0, r)] = (short)(d.x & 0xffff);
            Vs[vswz(c * 8 + 1, r)] = (short)(d.x >> 16);
            Vs[vswz(c * 8 + 2, r)] = (short)(d.y & 0xffff);
            Vs[vswz(c * 8 + 3, r)] = (short)(d.y >> 16);
            Vs[vswz(c * 8 + 4, r)] = (short)(d.z & 0xffff);
            Vs[vswz(c * 8 + 5, r)] = (short)(d.z >> 16);
            Vs[vswz(c * 8 + 6, r)] = (short)(d.w & 0xffff);
            Vs[vswz(c * 8 + 7, r)] = (short)(d.w >> 16);
        }
        __syncthreads();

        float am[4][4];
#pragma unroll
        for (int t = 0; t < 4; t++)
#pragma unroll
            for (int r = 0; r < 4; r++)
                am[t][r] = am_base[(size_t)r * MB + m0 + t * 16 + c16];

        floatx4 S[4];
#pragma unroll
        for (int t = 0; t < 4; t++) {
            short8 kf0 = *(const short8*)&Ks[swz(t * 16 + c16, quad * 8)];
            short8 kf1 = *(const short8*)&Ks[swz(t * 16 + c16, 32 + quad * 8)];
            floatx4 s = floatx4{0.f, 0.f, 0.f, 0.f};
            s = __builtin_amdgcn_mfma_f32_16x16x32_bf16(qf0, kf0, s, 0, 0, 0);
            s = __builtin_amdgcn_mfma_f32_16x16x32_bf16(qf1, kf1, s, 0, 0, 0);
            S[t] = s;
        }

#pragma unroll
        for (int t = 0; t < 4; t++)
#pragma unroll
            for (int r = 0; r < 4; r++) {
                float p = __expf(fmaf(S[t][r], sdp, am[t][r] * mp));
                l[r] += p;
                Ps[w][swz(quad * 4 + r, t * 16 + c16)] = (short)f2bf(p);
            }
        __threadfence_block();
        short8 pf0 = *(const short8*)&Ps[w][swz(c16, quad * 8)];
        short8 pf1 = *(const short8*)&Ps[w][swz(c16, 32 + quad * 8)];

#pragma unroll
        for (int dt = 0; dt < 4; dt++) {
            short8 vf0 = *(const short8*)&Vs[vswz(dt * 16 + c16, quad * 8)];
            short8 vf1 = *(const short8*)&Vs[vswz(dt * 16 + c16, 32 + quad * 8)];
            O[dt] = __builtin_amdgcn_mfma_f32_16x16x32_bf16(pf0, vf0, O[dt], 0, 0, 0);
            O[dt] = __builtin_amdgcn_mfma_f32_16x16x32_bf16(pf1, vf1, O[dt], 0, 0, 0);
        }
    }

    // quad-wide row sums (16 lanes each hold partial over their cols)
#pragma unroll
    for (int r = 0; r < 4; r++) {
        float s = l[r];
        s += __shfl_xor(s, 1);
        s += __shfl_xor(s, 2);
        s += __shfl_xor(s, 4);
        s += __shfl_xor(s, 8);
        l[r] = s;
    }
    if (c16 == 0) {
#pragma unroll
        for (int r = 0; r < 4; r++)
            lpart[((size_t)(sp * 16 + bh)) * NB + q0 + w * 16 + quad * 4 + r] = l[r];
    }
#pragma unroll
    for (int dt = 0; dt < 4; dt++)
#pragma unroll
        for (int r = 0; r < 4; r++) {
            size_t row = (size_t)sp * 4096 + b * NB + q0 + w * 16 + quad * 4 + r;
            Opart[row * 512 + h * 64 + dt * 16 + c16] = O[dt][r];
        }
}

// ---------------------------------------------------------------------------
// Combine the two M-splits: ao = (O0+O1)/(l0+l1), bf16.
// ---------------------------------------------------------------------------
__launch_bounds__(256)
__global__ void combine_splits(const float* __restrict__ Opart, const float* __restrict__ lpart,
                               unsigned short* __restrict__ ao) {
    int idx = blockIdx.x * 256 + threadIdx.x;       // one float4-group each
    int row = idx >> 7;                              // 4096 rows, 128 groups/row
    int col = (idx & 127) << 2;
    int b = row >> 11, n = row & 2047, h = col >> 6;
    float l0 = lpart[(size_t)(b * 8 + h) * NB + n];
    float l1 = lpart[(size_t)(16 + b * 8 + h) * NB + n];
    float rinv = 1.0f / (l0 + l1);
    float4 o0 = *(const float4*)(Opart + (size_t)row * 512 + col);
    float4 o1 = *(const float4*)(Opart + ((size_t)4096 + row) * 512 + col);
    uint2 o;
    o.x = (unsigned int)f2bf((o0.x + o1.x) * rinv) | ((unsigned int)f2bf((o0.y + o1.y) * rinv) << 16);
    o.y = (unsigned int)f2bf((o0.z + o1.z) * rinv) | ((unsigned int)f2bf((o0.w + o1.w) * rinv) << 16);
    *(uint2*)(ao + (size_t)row * 512 + col) = o;
}

extern "C" void kernel_launch(void* const* d_in, const int* in_sizes, int n_in,
                              void* d_out, int out_size, void* d_ws, size_t ws_size,
                              hipStream_t stream) {
    const float* x         = (const float*)d_in[0];
    const float* x1        = (const float*)d_in[1];
    const float* attn_mat  = (const float*)d_in[2];
    const float* dots_para = (const float*)d_in[3];
    const float* mat_para  = (const float*)d_in[4];
    const float* W_qv      = (const float*)d_in[5];
    const float* W_k       = (const float*)d_in[6];
    const float* W_out     = (const float*)d_in[7];
    const float* b_out     = (const float*)d_in[8];
    float* out = (float*)d_out;

    unsigned short* xb    = (unsigned short*)d_ws;                  // [4096,512]
    unsigned short* x1b   = xb    + (size_t)4096 * 512;             // [4096,512]
    unsigned short* qvbf  = x1b   + (size_t)4096 * 512;             // [4096,1024]
    unsigned short* kbf   = qvbf  + (size_t)4096 * 1024;            // [4096,512]
    unsigned short* aobf  = kbf   + (size_t)4096 * 512;             // [4096,512]
    unsigned short* Wqvt  = aobf  + (size_t)4096 * 512;             // [1024,512]
    unsigned short* Wkt   = Wqvt  + (size_t)1024 * 512;             // [512,512]
    unsigned short* Woutt = Wkt   + (size_t)512 * 512;              // [512,512]
    float*          Opart = (float*)(Woutt + (size_t)512 * 512);    // [2,4096,512]
    float*          lpart = Opart + (size_t)2 * 4096 * 512;         // [2,16,2048]

    dim3 blk(256);
    cvt_bf16<<<2048, blk, 0, stream>>>(x, xb, 524288);
    cvt_bf16<<<2048, blk, 0, stream>>>(x1, x1b, 524288);
    transpose_cvt<<<dim3(8, 16), blk, 0, stream>>>(W_qv, Wqvt, 512, 1024);
    transpose_cvt<<<dim3(8, 8), blk, 0, stream>>>(W_k, Wkt, 512, 512);
    transpose_cvt<<<dim3(8, 8), blk, 0, stream>>>(W_out, Woutt, 512, 512);
    gemm_bt<1><<<dim3(64, 16), blk, 0, stream>>>(xb, Wqvt, nullptr, qvbf, 1024);
    gemm_bt<1><<<dim3(64, 8), blk, 0, stream>>>(x1b, Wkt, nullptr, kbf, 512);
    flash_attn<<<dim3(32, 16, 2), blk, 0, stream>>>(qvbf, kbf, attn_mat, dots_para, mat_para, Opart, lpart);
    combine_splits<<<2048, blk, 0, stream>>>(Opart, lpart, aobf);
    gemm_bt<0><<<dim3(64, 8), blk, 0, stream>>>(aobf, Woutt, b_out, out, 512);
}

// Round 3
// 449.831 us; speedup vs baseline: 1.2905x; 1.0329x over previous
//
#include <hip/hip_runtime.h>
#include <hip/hip_bf16.h>

#define NB 2048
#define MB 2048
#define SPLITS 4
#define MSP (MB / SPLITS)  // 512

typedef __attribute__((ext_vector_type(8))) short short8;
typedef __attribute__((ext_vector_type(4))) float floatx4;

__device__ __forceinline__ unsigned short f2bf(float f) {
    union { float f; unsigned int u; } v; v.f = f;
    unsigned int r = (v.u + 0x7FFFu + ((v.u >> 16) & 1u)) >> 16;
    return (unsigned short)r;
}

// XOR-swizzled LDS layout: 64 elems/row, 16B chunks swizzled by row low bits.
__device__ __forceinline__ int swz(int row, int k) {
    return (row << 6) + ((((k >> 3) ^ (row & 7))) << 3) + (k & 7);
}
// Variant for transposed-V (row = c*8+i pattern in staging).
__device__ __forceinline__ int vswz(int row, int k) {
    return (row << 6) + ((((k >> 3) ^ (row & 7) ^ ((row >> 3) & 7))) << 3) + (k & 7);
}

// ---------------------------------------------------------------------------
// prep: fused  cvt(x), cvt(x1), transpose_cvt(W_qv), (W_k), (W_out)
// blocks: [0,1024) cvt x | [1024,2048) cvt x1 | [2048,2176) Wqv | [2176,2240) Wk
//         | [2240,2304) Wout
// ---------------------------------------------------------------------------
__launch_bounds__(256)
__global__ void prep(const float* __restrict__ x, const float* __restrict__ x1,
                     const float* __restrict__ Wqv, const float* __restrict__ Wk,
                     const float* __restrict__ Wout,
                     unsigned short* __restrict__ xb, unsigned short* __restrict__ x1b,
                     unsigned short* __restrict__ Wqvt, unsigned short* __restrict__ Wkt,
                     unsigned short* __restrict__ Woutt) {
    __shared__ float t[64][65];
    const int bid = blockIdx.x, tid = threadIdx.x;
    if (bid < 2048) {
        const float* in = bid < 1024 ? x : x1;
        unsigned short* out = bid < 1024 ? xb : x1b;
        size_t off = ((size_t)(bid & 1023) * 256 + tid) * 8;
        float4 d0 = *(const float4*)(in + off);
        float4 d1 = *(const float4*)(in + off + 4);
        uint4 o;
        o.x = (unsigned int)f2bf(d0.x) | ((unsigned int)f2bf(d0.y) << 16);
        o.y = (unsigned int)f2bf(d0.z) | ((unsigned int)f2bf(d0.w) << 16);
        o.z = (unsigned int)f2bf(d1.x) | ((unsigned int)f2bf(d1.y) << 16);
        o.w = (unsigned int)f2bf(d1.z) | ((unsigned int)f2bf(d1.w) << 16);
        *(uint4*)(out + off) = o;
        return;
    }
    int tb = bid - 2048;
    const float* W; unsigned short* Wt; int N;
    if (tb < 128)      { W = Wqv;  Wt = Wqvt;  N = 1024; }
    else if (tb < 192) { tb -= 128; W = Wk;   Wt = Wkt;   N = 512; }
    else               { tb -= 192; W = Wout; Wt = Woutt; N = 512; }
    const int k0 = (tb & 7) * 64, n0 = (tb >> 3) * 64;
#pragma unroll
    for (int p = 0; p < 4; p++) {
        int idx = p * 256 + tid;
        int kr = idx >> 4, c4 = (idx & 15) << 2;
        float4 d = *(const float4*)(W + (size_t)(k0 + kr) * N + n0 + c4);
        t[kr][c4 + 0] = d.x; t[kr][c4 + 1] = d.y; t[kr][c4 + 2] = d.z; t[kr][c4 + 3] = d.w;
    }
    __syncthreads();
#pragma unroll
    for (int p = 0; p < 4; p++) {
        int idx = p * 256 + tid;
        int nr = idx >> 4, k4 = (idx & 15) << 2;
        uint2 o;
        o.x = (unsigned int)f2bf(t[k4 + 0][nr]) | ((unsigned int)f2bf(t[k4 + 1][nr]) << 16);
        o.y = (unsigned int)f2bf(t[k4 + 2][nr]) | ((unsigned int)f2bf(t[k4 + 3][nr]) << 16);
        *(uint2*)(Wt + (size_t)(n0 + nr) * 512 + k0 + k4) = o;
    }
}

// ---------------------------------------------------------------------------
// Shared 64x64-tile bf16 GEMM body (verified in R2): A [M][512], Bt [N][512],
// C = A @ Bt^T.
// ---------------------------------------------------------------------------
template <int OUT_BF16>
__device__ __forceinline__ void gemm64_body(const unsigned short* __restrict__ A,
                                            const unsigned short* __restrict__ Bt,
                                            const float* __restrict__ bias,
                                            void* __restrict__ Cp, int Nc, int m0, int n0,
                                            short* Al, short* Bl) {
    const int tid = threadIdx.x;
    const int w = tid >> 6, lane = tid & 63;
    const int quad = lane >> 4, c16 = lane & 15;
    const int wr = (w >> 1) * 32, wc = (w & 1) * 32;

    floatx4 acc[2][2];
#pragma unroll
    for (int i = 0; i < 2; i++)
#pragma unroll
        for (int j = 0; j < 2; j++) acc[i][j] = floatx4{0.f, 0.f, 0.f, 0.f};

    for (int kk = 0; kk < 512; kk += 64) {
        __syncthreads();
#pragma unroll
        for (int p = 0; p < 2; p++) {
            int id = p * 256 + tid;
            int row = id >> 3, c8 = (id & 7) << 3;
            *(uint4*)&Al[swz(row, c8)] = *(const uint4*)(A + (size_t)(m0 + row) * 512 + kk + c8);
            *(uint4*)&Bl[swz(row, c8)] = *(const uint4*)(Bt + (size_t)(n0 + row) * 512 + kk + c8);
        }
        __syncthreads();
#pragma unroll
        for (int kc = 0; kc < 2; kc++) {
            short8 af[2], bf[2];
#pragma unroll
            for (int mt = 0; mt < 2; mt++)
                af[mt] = *(const short8*)&Al[swz(wr + mt * 16 + c16, kc * 32 + quad * 8)];
#pragma unroll
            for (int nt = 0; nt < 2; nt++)
                bf[nt] = *(const short8*)&Bl[swz(wc + nt * 16 + c16, kc * 32 + quad * 8)];
#pragma unroll
            for (int mt = 0; mt < 2; mt++)
#pragma unroll
                for (int nt = 0; nt < 2; nt++)
                    acc[mt][nt] = __builtin_amdgcn_mfma_f32_16x16x32_bf16(af[mt], bf[nt], acc[mt][nt], 0, 0, 0);
        }
    }
#pragma unroll
    for (int mt = 0; mt < 2; mt++)
#pragma unroll
        for (int nt = 0; nt < 2; nt++)
#pragma unroll
            for (int r = 0; r < 4; r++) {
                int row = m0 + wr + mt * 16 + quad * 4 + r;
                int col = n0 + wc + nt * 16 + c16;
                float v = acc[mt][nt][r];
                if (OUT_BF16) {
                    ((unsigned short*)Cp)[(size_t)row * Nc + col] = f2bf(v);
                } else {
                    ((float*)Cp)[(size_t)row * Nc + col] = v + bias[col];
                }
            }
}

// Fused qv + k projection: blocks [0,1024) -> qv (Nc=1024), [1024,1536) -> k.
__launch_bounds__(256)
__global__ void gemm_qvk(const unsigned short* __restrict__ xb, const unsigned short* __restrict__ x1b,
                         const unsigned short* __restrict__ Wqvt, const unsigned short* __restrict__ Wkt,
                         unsigned short* __restrict__ qvbf, unsigned short* __restrict__ kbf) {
    __shared__ short Al[64 * 64];
    __shared__ short Bl[64 * 64];
    int bid = blockIdx.x;
    if (bid < 1024) {
        gemm64_body<1>(xb, Wqvt, nullptr, qvbf, 1024, (bid & 63) * 64, (bid >> 6) * 64, Al, Bl);
    } else {
        bid -= 1024;
        gemm64_body<1>(x1b, Wkt, nullptr, kbf, 512, (bid & 63) * 64, (bid >> 6) * 64, Al, Bl);
    }
}

__launch_bounds__(256)
__global__ void gemm_out(const unsigned short* __restrict__ A, const unsigned short* __restrict__ Bt,
                         const float* __restrict__ bias, float* __restrict__ C) {
    __shared__ short Al[64 * 64];
    __shared__ short Bl[64 * 64];
    gemm64_body<0>(A, Bt, bias, C, 512, blockIdx.x * 64, blockIdx.y * 64, Al, Bl);
}

// ---------------------------------------------------------------------------
// Flash attention v3: 128 q-rows/block (4 waves x 32 q), M-split=4, K/V
// double-buffered in LDS with register prefetch one tile ahead, attn_mat
// prefetched one tile ahead into regs, Q-LDS aliased as P-LDS after prologue.
// Single barrier per tile. No running max (|dots| bounded).
// ---------------------------------------------------------------------------
__launch_bounds__(256)
__global__ void flash_attn(const unsigned short* __restrict__ qv,
                           const unsigned short* __restrict__ kb,
                           const float* __restrict__ attn_mat,
                           const float* __restrict__ dots_para,
                           const float* __restrict__ mat_para,
                           float* __restrict__ Opart,
                           float* __restrict__ lpart) {
    __shared__ short QP[4][32 * 64];   // Q (as flat 128x64) then per-wave P
    __shared__ short Ks[2][64 * 64];
    __shared__ short Vs[2][64 * 64];   // transposed [d][m], vswz layout

    const int tid = threadIdx.x, w = tid >> 6, lane = tid & 63;
    const int quad = lane >> 4, c16 = lane & 15;
    const int q0 = blockIdx.x * 128;
    const int bh = blockIdx.y;
    const int sp = blockIdx.z;
    const int b = bh >> 3, h = bh & 7;
    const int ms = sp * MSP;

    const float log2e = 1.4426950408889634f;
    const float mp = mat_para[0] * log2e;
    const float sdp = dots_para[0] * 0.125f * log2e;

    // ---- stage Q (128 x 64), read frags, then alias QP as P-scratch ----
    short* QPf = (short*)QP;
#pragma unroll
    for (int p = 0; p < 4; p++) {
        int id = p * 256 + tid;
        int r = id >> 3, c = id & 7;
        *(uint4*)&QPf[swz(r, c * 8)] =
            *(const uint4*)(qv + (size_t)(b * NB + q0 + r) * 1024 + h * 64 + c * 8);
    }
    __syncthreads();
    short8 qf[2][2];
#pragma unroll
    for (int at = 0; at < 2; at++)
#pragma unroll
        for (int kc = 0; kc < 2; kc++)
            qf[at][kc] = *(const short8*)&QPf[swz(w * 32 + at * 16 + c16, kc * 32 + quad * 8)];
    short* Pw = &QPf[w * 2048];  // wave-private 32x64 region (same rows Q frags came from)

    // ---- prefetch helpers ----
    const int sr = tid >> 3, sc = tid & 7;  // staging row/chunk for this thread (id & 511)
    uint4 kreg[2], vreg[2];
    auto loadKV = [&](int m) {
#pragma unroll
        for (int p = 0; p < 2; p++) {
            int r = p * 32 + sr;
            kreg[p] = *(const uint4*)(kb + (size_t)(b * MB + m + r) * 512 + h * 64 + sc * 8);
            vreg[p] = *(const uint4*)(qv + (size_t)(b * NB + m + r) * 1024 + 512 + h * 64 + sc * 8);
        }
    };
    auto storeKV = [&](int bufi) {
#pragma unroll
        for (int p = 0; p < 2; p++) {
            int r = p * 32 + sr;
            *(uint4*)&Ks[bufi][swz(r, sc * 8)] = kreg[p];
            uint4 d = vreg[p];
            Vs[bufi][vswz(sc * 8 + 0, r)] = (short)(d.x & 0xffff);
            Vs[bufi][vswz(sc * 8 + 1, r)] = (short)(d.x >> 16);
            Vs[bufi][vswz(sc * 8 + 2, r)] = (short)(d.y & 0xffff);
            Vs[bufi][vswz(sc * 8 + 3, r)] = (short)(d.y >> 16);
            Vs[bufi][vswz(sc * 8 + 4, r)] = (short)(d.z & 0xffff);
            Vs[bufi][vswz(sc * 8 + 5, r)] = (short)(d.z >> 16);
            Vs[bufi][vswz(sc * 8 + 6, r)] = (short)(d.w & 0xffff);
            Vs[bufi][vswz(sc * 8 + 7, r)] = (short)(d.w >> 16);
        }
    };
    const float* amp = attn_mat + ((size_t)bh * NB + q0 + w * 32 + quad * 4) * MB + c16;
    float amr[2][4][4];
    auto loadAM = [&](int m0_) {
#pragma unroll
        for (int at = 0; at < 2; at++)
#pragma unroll
            for (int r = 0; r < 4; r++)
#pragma unroll
                for (int t = 0; t < 4; t++)
                    amr[at][t][r] = amp[(size_t)(at * 16 + r) * MB + m0_ + t * 16];
    };

    // ---- prologue: tile0 staged to buf0; tile1 in regs; am(0) in regs ----
    loadKV(ms);
    storeKV(0);
    loadKV(ms + 64 < ms + MSP ? ms + 64 : ms);
    loadAM(ms);

    floatx4 O[2][4];
    float l[2][4];
#pragma unroll
    for (int at = 0; at < 2; at++)
#pragma unroll
        for (int i = 0; i < 4; i++) { O[at][i] = floatx4{0.f, 0.f, 0.f, 0.f}; l[at][i] = 0.f; }

    for (int it = 0; it < MSP / 64; it++) {
        const int m0 = ms + it * 64;
        const int buf = it & 1, nbuf = buf ^ 1;
        __syncthreads();                 // waves done reading buf^1; prefetches drained
        storeKV(nbuf);                   // stage tile it+1
        int mnn = m0 + 128; if (mnn >= ms + MSP) mnn = ms;
        loadKV(mnn);                     // issue global loads for tile it+2

        // S = Q K^T
        floatx4 S[2][4];
#pragma unroll
        for (int t = 0; t < 4; t++) {
            short8 kf0 = *(const short8*)&Ks[buf][swz(t * 16 + c16, quad * 8)];
            short8 kf1 = *(const short8*)&Ks[buf][swz(t * 16 + c16, 32 + quad * 8)];
#pragma unroll
            for (int at = 0; at < 2; at++) {
                floatx4 s = floatx4{0.f, 0.f, 0.f, 0.f};
                s = __builtin_amdgcn_mfma_f32_16x16x32_bf16(qf[at][0], kf0, s, 0, 0, 0);
                s = __builtin_amdgcn_mfma_f32_16x16x32_bf16(qf[at][1], kf1, s, 0, 0, 0);
                S[at][t] = s;
            }
        }

        // P = exp2(S*sdp + am*mp), row sums, store to wave-private LDS
#pragma unroll
        for (int at = 0; at < 2; at++)
#pragma unroll
            for (int t = 0; t < 4; t++)
#pragma unroll
                for (int r = 0; r < 4; r++) {
                    float p = exp2f(fmaf(S[at][t][r], sdp, amr[at][t][r] * mp));
                    l[at][r] += p;
                    Pw[swz(at * 16 + quad * 4 + r, t * 16 + c16)] = (short)f2bf(p);
                }
        int mnx = m0 + 64; if (mnx >= ms + MSP) mnx = ms;
        loadAM(mnx);                     // prefetch am for tile it+1
        __threadfence_block();

        // O += P V
        short8 pf[2][2];
#pragma unroll
        for (int at = 0; at < 2; at++)
#pragma unroll
            for (int kc = 0; kc < 2; kc++)
                pf[at][kc] = *(const short8*)&Pw[swz(at * 16 + c16, kc * 32 + quad * 8)];
#pragma unroll
        for (int dt = 0; dt < 4; dt++) {
            short8 vf0 = *(const short8*)&Vs[buf][vswz(dt * 16 + c16, quad * 8)];
            short8 vf1 = *(const short8*)&Vs[buf][vswz(dt * 16 + c16, 32 + quad * 8)];
#pragma unroll
            for (int at = 0; at < 2; at++) {
                O[at][dt] = __builtin_amdgcn_mfma_f32_16x16x32_bf16(pf[at][0], vf0, O[at][dt], 0, 0, 0);
                O[at][dt] = __builtin_amdgcn_mfma_f32_16x16x32_bf16(pf[at][1], vf1, O[at][dt], 0, 0, 0);
            }
        }
    }

    // row sums across the 16 lanes of each quad; write partial l and O
#pragma unroll
    for (int at = 0; at < 2; at++) {
#pragma unroll
        for (int r = 0; r < 4; r++) {
            float s = l[at][r];
            s += __shfl_xor(s, 1);
            s += __shfl_xor(s, 2);
            s += __shfl_xor(s, 4);
            s += __shfl_xor(s, 8);
            l[at][r] = s;
        }
        if (c16 == 0) {
#pragma unroll
            for (int r = 0; r < 4; r++)
                lpart[(size_t)(sp * 16 + bh) * NB + q0 + w * 32 + at * 16 + quad * 4 + r] = l[at][r];
        }
#pragma unroll
        for (int dt = 0; dt < 4; dt++)
#pragma unroll
            for (int r = 0; r < 4; r++) {
                size_t row = (size_t)sp * 4096 + b * NB + q0 + w * 32 + at * 16 + quad * 4 + r;
                Opart[row * 512 + h * 64 + dt * 16 + c16] = O[at][dt][r];
            }
    }
}

// ---------------------------------------------------------------------------
// Combine 4 M-splits: ao = (sum O_s) / (sum l_s), bf16.
// ---------------------------------------------------------------------------
__launch_bounds__(256)
__global__ void combine_splits(const float* __restrict__ Opart, const float* __restrict__ lpart,
                               unsigned short* __restrict__ ao) {
    int idx = blockIdx.x * 256 + threadIdx.x;  // one float4-group; 4096 rows x 128 groups
    int row = idx >> 7;
    int col = (idx & 127) << 2;
    int b = row >> 11, n = row & 2047, h = col >> 6;
    float ls = 0.f;
    float4 o = {0.f, 0.f, 0.f, 0.f};
#pragma unroll
    for (int sp = 0; sp < SPLITS; sp++) {
        ls += lpart[(size_t)(sp * 16 + b * 8 + h) * NB + n];
        float4 os = *(const float4*)(Opart + ((size_t)sp * 4096 + row) * 512 + col);
        o.x += os.x; o.y += os.y; o.z += os.z; o.w += os.w;
    }
    float rinv = 1.0f / ls;
    uint2 pk;
    pk.x = (unsigned int)f2bf(o.x * rinv) | ((unsigned int)f2bf(o.y * rinv) << 16);
    pk.y = (unsigned int)f2bf(o.z * rinv) | ((unsigned int)f2bf(o.w * rinv) << 16);
    *(uint2*)(ao + (size_t)row * 512 + col) = pk;
}

extern "C" void kernel_launch(void* const* d_in, const int* in_sizes, int n_in,
                              void* d_out, int out_size, void* d_ws, size_t ws_size,
                              hipStream_t stream) {
    const float* x         = (const float*)d_in[0];
    const float* x1        = (const float*)d_in[1];
    const float* attn_mat  = (const float*)d_in[2];
    const float* dots_para = (const float*)d_in[3];
    const float* mat_para  = (const float*)d_in[4];
    const float* W_qv      = (const float*)d_in[5];
    const float* W_k       = (const float*)d_in[6];
    const float* W_out     = (const float*)d_in[7];
    const float* b_out     = (const float*)d_in[8];
    float* out = (float*)d_out;

    unsigned short* xb    = (unsigned short*)d_ws;                  // [4096,512]
    unsigned short* x1b   = xb    + (size_t)4096 * 512;
    unsigned short* qvbf  = x1b   + (size_t)4096 * 512;             // [4096,1024]
    unsigned short* kbf   = qvbf  + (size_t)4096 * 1024;            // [4096,512]
    unsigned short* aobf  = kbf   + (size_t)4096 * 512;             // [4096,512]
    unsigned short* Wqvt  = aobf  + (size_t)4096 * 512;             // [1024,512]
    unsigned short* Wkt   = Wqvt  + (size_t)1024 * 512;             // [512,512]
    unsigned short* Woutt = Wkt   + (size_t)512 * 512;              // [512,512]
    float*          Opart = (float*)(Woutt + (size_t)512 * 512);    // [4,4096,512]
    float*          lpart = Opart + (size_t)SPLITS * 4096 * 512;    // [4,16,2048]

    dim3 blk(256);
    prep<<<2304, blk, 0, stream>>>(x, x1, W_qv, W_k, W_out, xb, x1b, Wqvt, Wkt, Woutt);
    gemm_qvk<<<1536, blk, 0, stream>>>(xb, x1b, Wqvt, Wkt, qvbf, kbf);
    flash_attn<<<dim3(16, 16, SPLITS), blk, 0, stream>>>(qvbf, kbf, attn_mat, dots_para, mat_para, Opart, lpart);
    combine_splits<<<2048, blk, 0, stream>>>(Opart, lpart, aobf);
    gemm_out<<<dim3(64, 8), blk, 0, stream>>>(aobf, Woutt, b_out, out);
}